// Round 13
// baseline (324.455 us; speedup 1.0000x reference)
//
#include <hip/hip_runtime.h>
#include <hip/hip_bf16.h>
#include <cstdint>

#define HFEAT 128
#define CIN   256
#define FILL_S 64
#define FILL_C 16

typedef unsigned int  uint;
typedef unsigned short ushort;
typedef short bf16x8 __attribute__((ext_vector_type(8)));
typedef float f32x4  __attribute__((ext_vector_type(4)));

__device__ inline float bflo(uint u){ return __uint_as_float(u << 16); }
__device__ inline float bfhi(uint u){ return __uint_as_float(u & 0xffff0000u); }
__device__ inline uint  f2bf(float f){
  union { __hip_bfloat16 b; ushort u; } cvt;
  cvt.b = __float2bfloat16(f);   // RNE
  return (uint)cvt.u;
}

// ---------------- CSR build (rank-trick: atomics only in count) ----------------

// scan1 + dinv: per-1024-block inclusive scan of counts; dinv[i]=rsqrt(cnt+1)
__global__ void k_scan1(const int* __restrict__ counts, int n,
                        int* __restrict__ excl, int* __restrict__ bsum,
                        float* __restrict__ dinv){
  __shared__ int sm[1024];
  int t = threadIdx.x;
  int i = blockIdx.x*1024 + t;
  int v = (i < n) ? counts[i] : 0;
  if (i < n) dinv[i] = rsqrtf((float)v + 1.0f);
  sm[t] = v;
  __syncthreads();
  for (int off = 1; off < 1024; off <<= 1){
    int add = (t >= off) ? sm[t-off] : 0;
    __syncthreads();
    sm[t] += add;
    __syncthreads();
  }
  if (i < n) excl[i] = sm[t] - v;
  if (t == 1023) bsum[blockIdx.x] = sm[t];
}

// parallel block-sum scan (nb <= 1024)
__global__ void k_scan2(int* __restrict__ bsum, int nb){
  __shared__ int sm[1024];
  int t = threadIdx.x;
  int v = (t < nb) ? bsum[t] : 0;
  sm[t] = v;
  __syncthreads();
  for (int off = 1; off < 1024; off <<= 1){
    int add = (t >= off) ? sm[t-off] : 0;
    __syncthreads();
    sm[t] += add;
    __syncthreads();
  }
  if (t < nb) bsum[t] = sm[t] - v;   // exclusive
}

__global__ void k_scan3(const int* __restrict__ bsum, int n, int E,
                        int* __restrict__ rowoff){
  int i = blockIdx.x*blockDim.x + threadIdx.x;   // blockDim == 1024
  if (i < n) rowoff[i] += bsum[blockIdx.x];
  if (i == 0) rowoff[n] = E;
}

// slice-owned dense-write fill (r11 lesson: edge-order scatter writes hit the
// 800k x 64B partial-line wall ~51MB; rank makes position cursor-free, so
// invert: block (slice s, chunk c) streams dst coalesced and writes only its
// OWNED contiguous csr2 region -> lines fully written, no eviction waste).
__global__ void __launch_bounds__(256) k_fill2(const int* __restrict__ src,
                                               const int* __restrict__ dst,
                                               const ushort* __restrict__ rank,
                                               int E, int N,
                                               const int* __restrict__ rowoff,
                                               ushort* __restrict__ csr2){
  const int ns = (N + FILL_S - 1) / FILL_S;
  const int n0 = blockIdx.x * ns;
  const int n1 = min(n0 + ns, N);
  const int ec = (E + FILL_C - 1) / FILL_C;
  const int e0 = blockIdx.y * ec;
  const int e1 = min(e0 + ec, E);
  for (int e = e0 + threadIdx.x; e < e1; e += 256){
    int d = dst[e];
    if (d >= n0 && d < n1)
      csr2[rowoff[d] + (int)rank[e]] = (ushort)src[e];
  }
}

// -------- all three W fp32 [K][128] -> bf16 TRANSPOSED [128][K], one kernel --------

__global__ void k_cvt_all(const float* __restrict__ W1,  const float* __restrict__ Wmu,
                          const float* __restrict__ Wls, ushort* __restrict__ W1t,
                          ushort* __restrict__ Wmut, ushort* __restrict__ Wlst){
  int b = blockIdx.x, t = threadIdx.x;            // 384 blocks x 256 threads
  if (b < 128){
    W1t[b * CIN + t] = (ushort)f2bf(W1[(size_t)t * HFEAT + b]);
  } else if (b < 256){
    int nn = b - 128;
    if (t < HFEAT) Wmut[nn * HFEAT + t] = (ushort)f2bf(Wmu[(size_t)t * HFEAT + nn]);
  } else {
    int nn = b - 256;
    if (t < HFEAT) Wlst[nn * HFEAT + t] = (ushort)f2bf(Wls[(size_t)t * HFEAT + nn]);
  }
}

// ---------------- bf16-MFMA GEMM body (device fn) ----------------
// out[N,128] = A[N,K] @ W (W pre-transposed bf16 [128][K]).
// 64x128 tile / 256-thread block (4 waves). C/D layout per guide m89:
// col=lane&15, row=(lane>>4)*4+reg.

template<int K, bool IN_BF16, bool BIAS, bool OUT_BF16>
__device__ __forceinline__ void gemm_body(int bid,
                                          const void* __restrict__ Ain,
                                          const ushort* __restrict__ Wt,
                                          const float* __restrict__ bias,
                                          void* __restrict__ outv,
                                          int n,
                                          ushort (*Abuf)[72], ushort (*Bbuf)[72]){
  const int tid  = threadIdx.x;
  const int w    = tid >> 6;
  const int l    = tid & 63;
  const int l15  = l & 15;
  const int lhi  = l >> 4;          // 0..3
  const int row0 = bid * 64;

  const int ar = tid >> 2;          // 0..63
  const int aq = tid & 3;           // 0..3
  int arow = row0 + ar; if (arow >= n) arow = n - 1;

  f32x4 acc[8];
  #pragma unroll
  for (int t = 0; t < 8; t++) acc[t] = (f32x4){0.f, 0.f, 0.f, 0.f};

  const int NT = K / 64;
  #pragma unroll
  for (int kt = 0; kt < NT; ++kt){
    if (IN_BF16){
      const ushort* ap = (const ushort*)Ain + (size_t)arow * K + aq * 16 + kt * 64;
      uint4 v0 = *(const uint4*)(ap);
      uint4 v1 = *(const uint4*)(ap + 8);
      *(uint4*)&Abuf[ar][aq * 16]     = v0;
      *(uint4*)&Abuf[ar][aq * 16 + 8] = v1;
    } else {
      const float* p = (const float*)Ain + (size_t)arow * K + aq * 16 + kt * 64;
      float4 v0 = *(const float4*)(p);
      float4 v1 = *(const float4*)(p + 4);
      float4 v2 = *(const float4*)(p + 8);
      float4 v3 = *(const float4*)(p + 12);
      uint4 pa, pb;
      pa.x = f2bf(v0.x) | (f2bf(v0.y) << 16);
      pa.y = f2bf(v0.z) | (f2bf(v0.w) << 16);
      pa.z = f2bf(v1.x) | (f2bf(v1.y) << 16);
      pa.w = f2bf(v1.z) | (f2bf(v1.w) << 16);
      pb.x = f2bf(v2.x) | (f2bf(v2.y) << 16);
      pb.y = f2bf(v2.z) | (f2bf(v2.w) << 16);
      pb.z = f2bf(v3.x) | (f2bf(v3.y) << 16);
      pb.w = f2bf(v3.z) | (f2bf(v3.w) << 16);
      *(uint4*)&Abuf[ar][aq * 16]     = pa;
      *(uint4*)&Abuf[ar][aq * 16 + 8] = pb;
    }
    #pragma unroll
    for (int j = 0; j < 4; ++j){
      int flat = tid + 256 * j;          // 0..1023
      int bn = flat >> 3;
      int bk = (flat & 7) * 8;
      uint4 v = *(const uint4*)(Wt + (size_t)bn * K + kt * 64 + bk);
      *(uint4*)&Bbuf[bn][bk] = v;
    }
    __syncthreads();

    #pragma unroll
    for (int ks = 0; ks < 2; ++ks){
      const int ko = ks * 32 + lhi * 8;
      bf16x8 af = *(bf16x8*)&Abuf[16 * w + l15][ko];
      #pragma unroll
      for (int nt = 0; nt < 8; ++nt){
        bf16x8 bf = *(bf16x8*)&Bbuf[nt * 16 + l15][ko];
        acc[nt] = __builtin_amdgcn_mfma_f32_16x16x32_bf16(af, bf, acc[nt], 0, 0, 0);
      }
    }
    __syncthreads();
  }

  float bv[8];
  #pragma unroll
  for (int nt = 0; nt < 8; ++nt) bv[nt] = BIAS ? bias[nt * 16 + l15] : 0.f;

  #pragma unroll
  for (int j = 0; j < 4; ++j){
    int r = row0 + 16 * w + lhi * 4 + j;
    if (r < n){
      if (OUT_BF16){
        ushort* orow = (ushort*)outv + (size_t)r * HFEAT + l15;
        #pragma unroll
        for (int nt = 0; nt < 8; ++nt)
          orow[nt * 16] = (ushort)f2bf(acc[nt][j] + bv[nt]);
      } else {
        float* orow = (float*)outv + (size_t)r * HFEAT + l15;
        #pragma unroll
        for (int nt = 0; nt < 8; ++nt)
          orow[nt * 16] = acc[nt][j] + bv[nt];
      }
    }
  }
}

// ---------------- fused: gemm1 || edge-count (+rank capture) ----------------
// GEMM blocks FIRST (long-running CU residents); count blocks stream through
// the remaining slots, atomic latency hidden under MFMA (r10/r11 lesson).

__global__ void __launch_bounds__(256) k_count_gemm1(const int* __restrict__ dst, int E,
                                                     int* __restrict__ counts,
                                                     ushort* __restrict__ rank,
                                                     int nbG,
                                                     const float* __restrict__ x,
                                                     const ushort* __restrict__ W1t,
                                                     ushort* __restrict__ t1, int n){
  __shared__ ushort Abuf[64][72];
  __shared__ ushort Bbuf[128][72];
  int b = blockIdx.x;
  if (b >= nbG){
    int e = (b - nbG) * 256 + threadIdx.x;
    if (e < E) rank[e] = (ushort)atomicAdd(&counts[dst[e]], 1);
    return;
  }
  gemm_body<CIN, false, false, true>(b, x, W1t, nullptr, t1, n, Abuf, Bbuf);
}

// plain gemm (gemm2: mu/ls via blockIdx.y)
template<int K, bool IN_BF16, bool BIAS, bool OUT_BF16>
__global__ void __launch_bounds__(256) k_gemm_mfma(const void* __restrict__ Ain,
                                                   const ushort* __restrict__ Wta,
                                                   const ushort* __restrict__ Wtb,
                                                   const float* __restrict__ ba,
                                                   const float* __restrict__ bb,
                                                   void* __restrict__ outa,
                                                   void* __restrict__ outb,
                                                   int n){
  __shared__ ushort Abuf[64][72];
  __shared__ ushort Bbuf[128][72];
  const ushort* Wt   = (blockIdx.y == 0) ? Wta : Wtb;
  const float*  bias = (blockIdx.y == 0) ? ba  : bb;
  void*         outv = (blockIdx.y == 0) ? outa : outb;
  gemm_body<K, IN_BF16, BIAS, OUT_BF16>(blockIdx.x, Ain, Wt, bias, outv, n, Abuf, Bbuf);
}

// ---------------- Aggregation (ushort CSR, unscaled bf16 table) ------------
// acc_i = sum_{j in N(i)} dinv_j*table[j] + dinv_i*table[i]   (self in quarter 0)
// RELU=1: out = bf16( relu(dinv_i*acc + bias) )   (unscaled h -> next table)
// RELU=0: out = bf16( dinv_i*acc )                (g for gemm2)
// Quarter-wave (16 lanes x uint4 = 256B) per edge row; 4 edges/iter, unroll 2.

template<int RELU>
__global__ void __launch_bounds__(256) k_agg(const ushort* __restrict__ in,
                                             const float* __restrict__ bias,
                                             const int* __restrict__ rowoff,
                                             const ushort* __restrict__ csr2,
                                             const float* __restrict__ dinv,
                                             ushort* __restrict__ out, int n){
  int gid  = blockIdx.x*blockDim.x + threadIdx.x;
  int node = gid >> 6;
  int lane = gid & 63;
  if (node >= n) return;
  const int w  = lane >> 4;
  const int q  = lane & 15;
  const int f0 = q * 8;

  float acc[8] = {0,0,0,0,0,0,0,0};

  const int e0 = rowoff[node], e1 = rowoff[node+1];
  #pragma unroll 2
  for (int e = e0 + w; e < e1; e += 4){
    int s = (int)csr2[e];
    float wv = dinv[s];
    uint4 v = *(const uint4*)(in + ((size_t)s << 7) + f0);
    acc[0] = fmaf(bflo(v.x), wv, acc[0]);
    acc[1] = fmaf(bfhi(v.x), wv, acc[1]);
    acc[2] = fmaf(bflo(v.y), wv, acc[2]);
    acc[3] = fmaf(bfhi(v.y), wv, acc[3]);
    acc[4] = fmaf(bflo(v.z), wv, acc[4]);
    acc[5] = fmaf(bfhi(v.z), wv, acc[5]);
    acc[6] = fmaf(bflo(v.w), wv, acc[6]);
    acc[7] = fmaf(bfhi(v.w), wv, acc[7]);
  }
  if (w == 0){   // self term: dinv_i * table[i]
    float di = dinv[node];
    uint4 v = *(const uint4*)(in + ((size_t)node << 7) + f0);
    acc[0] = fmaf(bflo(v.x), di, acc[0]);
    acc[1] = fmaf(bfhi(v.x), di, acc[1]);
    acc[2] = fmaf(bflo(v.y), di, acc[2]);
    acc[3] = fmaf(bfhi(v.y), di, acc[3]);
    acc[4] = fmaf(bflo(v.z), di, acc[4]);
    acc[5] = fmaf(bfhi(v.z), di, acc[5]);
    acc[6] = fmaf(bflo(v.w), di, acc[6]);
    acc[7] = fmaf(bfhi(v.w), di, acc[7]);
  }
  #pragma unroll
  for (int j = 0; j < 8; j++){
    acc[j] += __shfl_xor(acc[j], 16);
    acc[j] += __shfl_xor(acc[j], 32);
  }

  if (w == 0){
    float di = dinv[node];
    uint4 p;
    if (RELU){
      float4 b0 = *(const float4*)&bias[f0];
      float4 b1 = *(const float4*)&bias[f0 + 4];
      float r0 = fmaxf(fmaf(acc[0], di, b0.x), 0.f);
      float r1 = fmaxf(fmaf(acc[1], di, b0.y), 0.f);
      float r2 = fmaxf(fmaf(acc[2], di, b0.z), 0.f);
      float r3 = fmaxf(fmaf(acc[3], di, b0.w), 0.f);
      float r4 = fmaxf(fmaf(acc[4], di, b1.x), 0.f);
      float r5 = fmaxf(fmaf(acc[5], di, b1.y), 0.f);
      float r6 = fmaxf(fmaf(acc[6], di, b1.z), 0.f);
      float r7 = fmaxf(fmaf(acc[7], di, b1.w), 0.f);
      p.x = f2bf(r0) | (f2bf(r1) << 16);
      p.y = f2bf(r2) | (f2bf(r3) << 16);
      p.z = f2bf(r4) | (f2bf(r5) << 16);
      p.w = f2bf(r6) | (f2bf(r7) << 16);
    } else {
      p.x = f2bf(acc[0] * di) | (f2bf(acc[1] * di) << 16);
      p.y = f2bf(acc[2] * di) | (f2bf(acc[3] * di) << 16);
      p.z = f2bf(acc[4] * di) | (f2bf(acc[5] * di) << 16);
      p.w = f2bf(acc[6] * di) | (f2bf(acc[7] * di) << 16);
    }
    *(uint4*)(out + ((size_t)node << 7) + f0) = p;
  }
}

// ---------------- launch ----------------

extern "C" void kernel_launch(void* const* d_in, const int* in_sizes, int n_in,
                              void* d_out, int out_size, void* d_ws, size_t ws_size,
                              hipStream_t stream){
  const float* x   = (const float*)d_in[0];
  const int*   ei  = (const int*)  d_in[1];
  const float* W1  = (const float*)d_in[2];
  const float* b1  = (const float*)d_in[3];
  const float* Wmu = (const float*)d_in[4];
  const float* bmu = (const float*)d_in[5];
  const float* Wls = (const float*)d_in[6];
  const float* bls = (const float*)d_in[7];
  int N = in_sizes[0] / CIN;
  int E = in_sizes[1] / 2;
  const int* src = ei;
  const int* dst = ei + E;
  float* out = (float*)d_out;

  char* w = (char*)d_ws;
  auto alloc = [&](size_t bytes)->char*{
    char* p = w; w += (bytes + 255) & ~(size_t)255; return p;
  };
  ushort* t1    = (ushort*)alloc((size_t)N*HFEAT*2);  // bf16 x@W1 (unscaled table 1)
  ushort* t2    = (ushort*)alloc((size_t)N*HFEAT*2);  // bf16 h   (unscaled table 2)
  ushort* gb    = (ushort*)alloc((size_t)N*HFEAT*2);  // bf16 g   (gemm2 input)
  ushort* W1bt  = (ushort*)alloc((size_t)HFEAT*CIN*2);  // bf16 W1^T  [128][256]
  ushort* Wmut  = (ushort*)alloc((size_t)HFEAT*HFEAT*2);// bf16 Wmu^T [128][128]
  ushort* Wlst  = (ushort*)alloc((size_t)HFEAT*HFEAT*2);// bf16 Wls^T [128][128]
  int*   counts = (int*)   alloc((size_t)N*4);
  float* dinv   = (float*) alloc((size_t)N*4);
  int*   rowoff = (int*)   alloc(((size_t)N+1)*4);
  ushort* rank  = (ushort*)alloc((size_t)E*2);
  int*   bsum   = (int*)   alloc(1024*4);
  ushort* csr2  = (ushort*)alloc((size_t)E*2);

  int nbE  = (E + 255) / 256;
  int nbS  = (N + 1023) / 1024;
  int nbG  = (N + 63) / 64;

  hipMemsetAsync(counts, 0, (size_t)N*4, stream);
  k_cvt_all <<<384, 256, 0, stream>>>(W1, Wmu, Wls, W1bt, Wmut, Wlst);
  // fused: gemm1 (blocks 0..nbG-1, CU residents) || count+rank (blocks nbG..)
  k_count_gemm1<<<nbG + nbE, 256, 0, stream>>>(dst, E, counts, rank, nbG,
                                               x, W1bt, t1, N);
  k_scan1   <<<nbS, 1024, 0, stream>>>(counts, N, rowoff, bsum, dinv);
  k_scan2   <<<1, 1024, 0, stream>>>(bsum, nbS);
  k_scan3   <<<nbS, 1024, 0, stream>>>(bsum, N, E, rowoff);
  k_fill2   <<<dim3(FILL_S, FILL_C), 256, 0, stream>>>(src, dst, rank, E, N,
                                                       rowoff, csr2);

  int aggBlocks = (int)(((size_t)N*64 + 255) / 256);
  // agg1: t2 = relu(dinv_i*(sum dinv_s*t1[s] + dinv_i*t1[i]) + b1)
  k_agg<1><<<aggBlocks, 256, 0, stream>>>(t1, b1, rowoff, csr2, dinv, t2, N);
  // agg2: gb = dinv_i*(sum dinv_s*t2[s] + dinv_i*t2[i])
  k_agg<0><<<aggBlocks, 256, 0, stream>>>(t2, nullptr, rowoff, csr2, dinv, gb, N);
  // gemm2: out = gb @ {Wmu,Wls} + {bmu,bls}, fp32
  k_gemm_mfma<HFEAT, true, true, false><<<dim3(nbG, 2), 256, 0, stream>>>(
      gb, Wmut, Wlst, bmu, bls, out, out + (size_t)N*HFEAT, N);
}